// Round 4
// baseline (202.079 us; speedup 1.0000x reference)
//
#include <hip/hip_runtime.h>

// DynamicMaskHead fused kernel:
//   x = concat(rel_coords(2), mask_feats[im_ind](8))  -> 10ch
//   h0 = relu(W0(8x10) x + b0); h1 = relu(W1(8x8) h0 + b1); logit = W2(1x8) h1 + b2
//   out = aligned_bilinear(logits, factor=2)  (upsample, shift-by-1, crop)
//
// Fully fused: logits tile lives in LDS, never hits HBM.
// Output pixel (y,x): yy=max(y-1,0), xx=max(x-1,0); iy0=yy>>1, fy=(yy&1)*0.5;
// clamped neighbor rows/cols are baked into LDS tile content.

#define HH   128
#define WW   192
#define OHH  256
#define OWW  384
#define THY  32          // output tile height
#define TWX  128         // output tile width
#define LR   18          // logits tile rows = THY/2 + 2
#define LC   66          // logits tile cols = TWX/2 + 2
#define NPX  (LR*LC)     // 1188
#define NPARAMS 169

__global__ __launch_bounds__(256, 2)
void dmh_fused(const float* __restrict__ mask_feats,
               const float* __restrict__ params,
               const float* __restrict__ locs,
               const int*   __restrict__ im_inds,
               const int*   __restrict__ fpn,
               float* __restrict__ out)
{
    __shared__ float sp[NPARAMS];
    __shared__ float L[LR][LC];

    const int inst = blockIdx.z;
    const int tid  = threadIdx.x;

    if (tid < NPARAMS) sp[tid] = params[(size_t)inst * NPARAMS + tid];

    const int   im     = im_inds[inst];
    const float instx  = locs[2*inst];
    const float insty  = locs[2*inst + 1];
    const float invsoi = 1.0f / (float)(64 << fpn[inst]);   // SOI = 64<<lvl (exact pow2)

    const int oy0 = blockIdx.y * THY;
    const int ox0 = blockIdx.x * TWX;
    const int r0  = oy0 >> 1;
    const int c0  = ox0 >> 1;

    __syncthreads();

    const float* __restrict__ fbase = mask_feats + (size_t)im * 8 * HH * WW;

    // ---- phase 1: compute logits tile (5 pixels / thread) ----
    float xf[5][8];   // feature channels
    float xr[5][2];   // rel coords
    int   pix[5];
#pragma unroll
    for (int k = 0; k < 5; ++k) {
        int p = tid + 256*k;
        if (p > NPX-1) p = NPX-1;      // tail threads recompute last px (benign dup store)
        pix[k] = p;
        int lr = p / LC;
        int lc = p - lr*LC;
        int gy = r0 - 1 + lr; gy = gy < 0 ? 0 : (gy > HH-1 ? HH-1 : gy);
        int gx = c0 - 1 + lc; gx = gx < 0 ? 0 : (gx > WW-1 ? WW-1 : gx);
        xr[k][0] = (instx - (float)(gx*8 + 4)) * invsoi;
        xr[k][1] = (insty - (float)(gy*8 + 4)) * invsoi;
        const float* fp = fbase + gy*WW + gx;
#pragma unroll
        for (int c = 0; c < 8; ++c)
            xf[k][c] = fp[c*HH*WW];
    }

    // layer 0: 8 out <- 10 in, relu.  Weights hoisted per-o, amortized over 5 px.
    float h0[5][8];
#pragma unroll
    for (int o = 0; o < 8; ++o) {
        const float w0 = sp[o*10 + 0];
        const float w1 = sp[o*10 + 1];
        float wc[8];
#pragma unroll
        for (int c = 0; c < 8; ++c) wc[c] = sp[o*10 + 2 + c];
        const float b = sp[152 + o];
#pragma unroll
        for (int k = 0; k < 5; ++k) {
            float a = w0*xr[k][0] + w1*xr[k][1];
#pragma unroll
            for (int c = 0; c < 8; ++c) a += wc[c]*xf[k][c];
            h0[k][o] = fmaxf(a + b, 0.0f);
        }
    }

    // layer 1: 8 <- 8, relu
    float h1[5][8];
#pragma unroll
    for (int o = 0; o < 8; ++o) {
        float wv[8];
#pragma unroll
        for (int i = 0; i < 8; ++i) wv[i] = sp[80 + o*8 + i];
        const float b = sp[160 + o];
#pragma unroll
        for (int k = 0; k < 5; ++k) {
            float a = wv[0]*h0[k][0];
#pragma unroll
            for (int i = 1; i < 8; ++i) a += wv[i]*h0[k][i];
            h1[k][o] = fmaxf(a + b, 0.0f);
        }
    }

    // layer 2: 1 <- 8, store to LDS tile
    {
        float wv[8];
#pragma unroll
        for (int i = 0; i < 8; ++i) wv[i] = sp[144 + i];
        const float b = sp[168];
#pragma unroll
        for (int k = 0; k < 5; ++k) {
            float a = wv[0]*h1[k][0];
#pragma unroll
            for (int i = 1; i < 8; ++i) a += wv[i]*h1[k][i];
            ((float*)L)[pix[k]] = a + b;
        }
    }

    __syncthreads();

    // ---- phase 2: aligned bilinear 2x, float4 stores ----
    // thread -> 4 consecutive x outputs; even base xb=2m needs logits cols m-1..m+2
    float* __restrict__ obase = out + (size_t)inst * OHH * OWW;
#pragma unroll
    for (int j = 0; j < 4; ++j) {
        const int yl = (tid >> 5) + 8*j;
        const int xq = (tid & 31) * 4;
        const int y  = oy0 + yl;
        const int yy = (y > 0) ? (y - 1) : 0;
        const int iy0 = yy >> 1;
        const float fy = (yy & 1) ? 0.5f : 0.0f;
        const int ly = iy0 - r0 + 1;       // row iy0 lives at LDS row iy0-(r0-1)
        const int m  = (ox0 + xq) >> 1;
        const int lx = m - c0;             // LDS col of global logits col m-1
        float t[4];
#pragma unroll
        for (int i = 0; i < 4; ++i) {
            const float a  = L[ly  ][lx + i];
            const float bb = L[ly+1][lx + i];
            t[i] = a*(1.0f - fy) + bb*fy;  // rows first (matches reference axis order)
        }
        float4 r;
        r.x = 0.5f*t[0] + 0.5f*t[1];   // x even  : fx=0.5 between cols m-1,m
        r.y = t[1];                    // x odd   : fx=0, col m
        r.z = 0.5f*t[1] + 0.5f*t[2];   // x even  : cols m,m+1
        r.w = t[2];                    // x odd   : col m+1
        *(float4*)(obase + (size_t)y*OWW + ox0 + xq) = r;
    }
}

extern "C" void kernel_launch(void* const* d_in, const int* in_sizes, int n_in,
                              void* d_out, int out_size, void* d_ws, size_t ws_size,
                              hipStream_t stream) {
    const float* mask_feats = (const float*)d_in[0];
    const float* params     = (const float*)d_in[1];
    const float* locs       = (const float*)d_in[2];
    const int*   im_inds    = (const int*)d_in[3];
    const int*   fpn        = (const int*)d_in[4];
    float*       out        = (float*)d_out;

    const int n_inst = in_sizes[1] / NPARAMS;   // 400
    dim3 grid(OWW/TWX, OHH/THY, n_inst);        // (3, 8, 400)
    dmh_fused<<<grid, 256, 0, stream>>>(mask_feats, params, locs, im_inds, fpn, out);
}